// Round 3
// baseline (7963.978 us; speedup 1.0000x reference)
//
#include <hip/hip_runtime.h>
#include <math.h>

// ============================================================================
// Seq2Seq decode: fully-fused persistent kernel, v3.
//
// v2 post-mortem: VALUBusy 60%, Occupancy 23.5% (2 waves/SIMD), FETCH 2.9 GB
// (per-step 7 MB weight sweep > 4 MB XCD L2 -> cyclic-LRU ~0% hit, every
// weight read is an L2 miss served by L3 at ~500 cyc). Latency-bound.
// v3: 1024 threads = 16 waves = 4 waves/SIMD (2x stall coverage), per-thread
// tile 1 unit x 4 gates x 4 rows (acc 16 VGPR -> block fits <=128 VGPR),
// pointer-bump weight addressing (imm offsets, ~8x less address VALU).
//
// Geometry:
//   wave c (0..15) owns gate-cols [c*64, c*64+64); lane: cg = lane&15,
//   rg = lane>>4; thread owns unit u = c*16+cg (4 gates) x 4 rows (rg*4..+3).
//   gate virtual col j (0..3): W row = j*256 + u.
//
// Repacked weights (float4 quads along k): quad = q*1024 + c*64 + j*16 + cg
//   -> per (q,j) a wave reads 16 consecutive quads = 256 B, coalesced.
// lin: quad = q*256 + c*16 + cg (col n = c*16+cg).
//
// LDS X[1152][16]: rows 0..255 prob | 256..383 tags | 384..639 h0 |
//   640..895 h1 | 896..1151 h2. Layer inputs are contiguous row ranges:
//   L0 K=640 rows 0..639; L1 K=512 rows 384..895; L2 K=512 rows 640..1151;
//   lin K=256 rows 896..1151. Same plan + barrier structure as v2 (verified).
// ============================================================================

typedef float v4 __attribute__((ext_vector_type(4)));

constexpr int Bsz   = 4096;
constexpr int AA    = 256;
constexpr int STEPS = 30;
constexpr int LDP   = 31 * AA;                       // 7936
constexpr long long PROB_N = (long long)Bsz * 31 * AA;

constexpr int WP0_Q = 160 * 1024;                    // L0: K=640
constexpr int WP1_Q = 128 * 1024;                    // L1: K=512
constexpr int WP2_Q = 128 * 1024;                    // L2: K=512
constexpr int WPL_Q = 64 * 256;                      // lin: K=256
constexpr int WP1_BASE = WP0_Q;
constexpr int WP2_BASE = WP1_BASE + WP1_Q;
constexpr int WPL_BASE = WP2_BASE + WP2_Q;
constexpr int WP_TOTAL = WPL_BASE + WPL_Q;           // 442368 quads = 7.08 MB

constexpr int XROWS = 1152;

__device__ __forceinline__ float sigf(float x) { return 1.0f / (1.0f + expf(-x)); }

// ---------------------------------------------------------------------------
// One-time weight repack into wave-contiguous layout (v3 mapping).
// ---------------------------------------------------------------------------
__global__ void repack_kernel(const float* __restrict__ Wih0, const float* __restrict__ Whh0,
                              const float* __restrict__ Wih12, const float* __restrict__ Whh12,
                              const float* __restrict__ linW, float* __restrict__ ws)
{
    int t = blockIdx.x * 256 + threadIdx.x;          // quad index, exact grid
    v4 val;
    if (t < WP1_BASE) {                              // layer 0, fused K = 640
        int cg = t & 15, j = (t >> 4) & 3, c = (t >> 6) & 15, q = t >> 10;
        int grow = j * 256 + c * 16 + cg;
        int k4 = q * 4;
        const float* src = (k4 < 384) ? (Wih0 + grow * 384 + k4)          // [prob|tags]
                                      : (Whh0 + grow * 256 + (k4 - 384)); // h0
        val = *reinterpret_cast<const v4*>(src);
    } else if (t < WP2_BASE) {                       // layer 1, K = 512
        int tt = t - WP1_BASE;
        int cg = tt & 15, j = (tt >> 4) & 3, c = (tt >> 6) & 15, q = tt >> 10;
        int grow = j * 256 + c * 16 + cg;
        int k4 = q * 4;
        const float* src = (k4 < 256) ? (Wih12 + grow * 256 + k4)
                                      : (Whh12 + grow * 256 + (k4 - 256));
        val = *reinterpret_cast<const v4*>(src);
    } else if (t < WPL_BASE) {                       // layer 2, K = 512
        int tt = t - WP2_BASE;
        int cg = tt & 15, j = (tt >> 4) & 3, c = (tt >> 6) & 15, q = tt >> 10;
        int grow = j * 256 + c * 16 + cg;
        int k4 = q * 4;
        const float* src = (k4 < 256) ? (Wih12 + 262144 + grow * 256 + k4)
                                      : (Whh12 + 262144 + grow * 256 + (k4 - 256));
        val = *reinterpret_cast<const v4*>(src);
    } else {                                         // lin, K = 256
        int tt = t - WPL_BASE;
        int cg = tt & 15, c = (tt >> 4) & 15, q = tt >> 8;
        int n = c * 16 + cg;
        val = *reinterpret_cast<const v4*>(linW + n * 256 + q * 4);
    }
    reinterpret_cast<v4*>(ws)[t] = val;
}

#define FMA_BLOCK(W, Xv)                                   \
    _Pragma("unroll")                                      \
    for (int k = 0; k < 4; k++)                            \
        _Pragma("unroll")                                  \
        for (int j = 0; j < 4; j++)                        \
            _Pragma("unroll")                              \
            for (int r = 0; r < 4; r++)                    \
                acc[j][r] += W[j][k] * Xv[k][r];

// ---------------------------------------------------------------------------
// LSTM layer phase: GEMM (K = 4*Q) + cell epilogue. Per-thread 1 unit.
// wq: repacked base + c*64 + cg; chunk stride 1024 quads (pointer-bumped).
// ---------------------------------------------------------------------------
template<int Q>
__device__ __forceinline__ void lstm_phase(
    const v4* __restrict__ wq, const float* __restrict__ xb,
    const float* __restrict__ bihL, const float* __restrict__ bhhL,
    int u, int rg, float (&cr)[4], float* __restrict__ dst)
{
    float bs[4];
    #pragma unroll
    for (int j = 0; j < 4; j++) bs[j] = bihL[j * 256 + u] + bhhL[j * 256 + u];

    float acc[4][4];
    #pragma unroll
    for (int j = 0; j < 4; j++)
        #pragma unroll
        for (int r = 0; r < 4; r++) acc[j][r] = 0.0f;

    const v4* xq = reinterpret_cast<const v4*>(xb) + rg;
    const v4* wp = wq;
    v4 wa[4], wb[4], xa[4], xc[4];

    #pragma unroll
    for (int j = 0; j < 4; j++) wa[j] = wp[j * 16];
    wp += 1024;
    #pragma unroll
    for (int k = 0; k < 4; k++) xa[k] = xq[k * 4];

    #pragma unroll 1
    for (int q = 0; q < Q - 2; q += 2) {
        #pragma unroll
        for (int j = 0; j < 4; j++) wb[j] = wp[j * 16];
        wp += 1024;
        #pragma unroll
        for (int k = 0; k < 4; k++) xc[k] = xq[(q + 1) * 16 + k * 4];
        FMA_BLOCK(wa, xa)
        #pragma unroll
        for (int j = 0; j < 4; j++) wa[j] = wp[j * 16];
        wp += 1024;
        #pragma unroll
        for (int k = 0; k < 4; k++) xa[k] = xq[(q + 2) * 16 + k * 4];
        FMA_BLOCK(wb, xc)
    }
    // tail: chunk Q-2 in wa/xa; load and do chunk Q-1
    #pragma unroll
    for (int j = 0; j < 4; j++) wb[j] = wp[j * 16];
    #pragma unroll
    for (int k = 0; k < 4; k++) xc[k] = xq[(Q - 1) * 16 + k * 4];
    FMA_BLOCK(wa, xa)
    FMA_BLOCK(wb, xc)

    __syncthreads();   // all waves done READING xb before h region is overwritten
    v4 hv;
    #pragma unroll
    for (int r = 0; r < 4; r++) {
        float gi = acc[0][r] + bs[0];
        float gf = acc[1][r] + bs[1];
        float gg = acc[2][r] + bs[2];
        float go = acc[3][r] + bs[3];
        float cn = sigf(gf) * cr[r] + sigf(gi) * tanhf(gg);
        cr[r] = cn;
        hv[r] = sigf(go) * tanhf(cn);
    }
    *reinterpret_cast<v4*>(dst + u * 16 + rg * 4) = hv;
    __syncthreads();   // h visible before next phase reads it
}

// ---------------------------------------------------------------------------
// lin phase: pred = sigmoid(h2 @ linW^T + b). Per-thread 1 col (n = u).
// chunk stride 256 quads (pointer-bumped).
// ---------------------------------------------------------------------------
__device__ __forceinline__ void lin_phase(
    const v4* __restrict__ wq, const float* __restrict__ xb,
    const float* __restrict__ linb,
    int n, int rg, int m0, int t,
    float* __restrict__ probdst, float* __restrict__ out)
{
    float b = linb[n];
    float acc[4] = {0.f, 0.f, 0.f, 0.f};
    const v4* xq = reinterpret_cast<const v4*>(xb) + rg;
    const v4* wp = wq;
    v4 wa, wb, xa[4], xc[4];

    wa = wp[0]; wp += 256;
    #pragma unroll
    for (int k = 0; k < 4; k++) xa[k] = xq[k * 4];

    #pragma unroll 1
    for (int q = 0; q < 62; q += 2) {
        wb = wp[0]; wp += 256;
        #pragma unroll
        for (int k = 0; k < 4; k++) xc[k] = xq[(q + 1) * 16 + k * 4];
        #pragma unroll
        for (int k = 0; k < 4; k++)
            #pragma unroll
            for (int r = 0; r < 4; r++) acc[r] += wa[k] * xa[k][r];
        wa = wp[0]; wp += 256;
        #pragma unroll
        for (int k = 0; k < 4; k++) xa[k] = xq[(q + 2) * 16 + k * 4];
        #pragma unroll
        for (int k = 0; k < 4; k++)
            #pragma unroll
            for (int r = 0; r < 4; r++) acc[r] += wb[k] * xc[k][r];
    }
    wb = wp[0];
    #pragma unroll
    for (int k = 0; k < 4; k++) xc[k] = xq[63 * 16 + k * 4];
    #pragma unroll
    for (int k = 0; k < 4; k++)
        #pragma unroll
        for (int r = 0; r < 4; r++) acc[r] += wa[k] * xa[k][r];
    #pragma unroll
    for (int k = 0; k < 4; k++)
        #pragma unroll
        for (int r = 0; r < 4; r++) acc[r] += wb[k] * xc[k][r];

    __syncthreads();   // everyone done reading h2; old prob no longer needed
    v4 pv;
    #pragma unroll
    for (int r = 0; r < 4; r++) pv[r] = sigf(acc[r] + b);
    *reinterpret_cast<v4*>(probdst + n * 16 + rg * 4) = pv;
    #pragma unroll
    for (int r = 0; r < 4; r++)
        out[(long long)(m0 + rg * 4 + r) * LDP + (long long)(t + 1) * AA + n] = pv[r];
    __syncthreads();   // prob LDS visible for argmax + next step
}

// ---------------------------------------------------------------------------
// Persistent decode kernel: 256 blocks x 16 rows, 16 waves, 30 steps fused.
// ---------------------------------------------------------------------------
__global__ __launch_bounds__(1024) void decode_kernel(
    const float* __restrict__ tags,
    const float* __restrict__ bih0, const float* __restrict__ bhh0,
    const float* __restrict__ bih12, const float* __restrict__ bhh12,
    const float* __restrict__ linb,
    const float* __restrict__ ws,
    float* __restrict__ out)
{
    __shared__ float X[XROWS * 16];      // 73728 B
    __shared__ float redv[1024];         // argmax partials [64 sb][16 rows]
    __shared__ int   redi[1024];

    const int tid  = threadIdx.x;
    const int c    = tid >> 6;
    const int lane = tid & 63;
    const int cg   = lane & 15;
    const int rg   = lane >> 4;
    const int u    = c * 16 + cg;
    const int m0   = blockIdx.x * 16;

    // ---- init: zero state, stage tags, one-hot(START=1) ----
    for (int i = tid; i < XROWS * 16; i += 1024) X[i] = 0.0f;
    __syncthreads();
    for (int i = tid; i < 128 * 16; i += 1024) {
        int m = i & 15, k = i >> 4;
        X[(256 + k) * 16 + m] = tags[(long long)(m0 + m) * 128 + k];
    }
    if (tid < 16) X[1 * 16 + tid] = 1.0f;                    // prob one-hot col 1
    for (int i = tid; i < 256 * 16; i += 1024) {
        int m = i >> 8, col = i & 255;
        out[(long long)(m0 + m) * LDP + col] = (col == 1) ? 1.0f : 0.0f;
    }
    __syncthreads();

    float cr0[4], cr1[4], cr2[4];
    #pragma unroll
    for (int r = 0; r < 4; r++) { cr0[r] = 0.f; cr1[r] = 0.f; cr2[r] = 0.f; }

    const v4* wsq = reinterpret_cast<const v4*>(ws);
    const v4* w0 = wsq + 0        + c * 64 + cg;
    const v4* w1 = wsq + WP1_BASE + c * 64 + cg;
    const v4* w2 = wsq + WP2_BASE + c * 64 + cg;
    const v4* wl = wsq + WPL_BASE + c * 16 + cg;

    float* hx0 = X + 384 * 16;   // h0 rows
    float* hx1 = X + 640 * 16;   // h1 rows
    float* hx2 = X + 896 * 16;   // h2 rows

    const int arow = tid & 15, sb = tid >> 4;    // sb in 0..63
    float* outputs = out + PROB_N;

    #pragma unroll 1
    for (int t = 0; t < STEPS; t++) {
        lstm_phase<160>(w0, X,   bih0,         bhh0,         u, rg, cr0, hx0);
        lstm_phase<128>(w1, hx0, bih12,        bhh12,        u, rg, cr1, hx1);
        lstm_phase<128>(w2, hx1, bih12 + 1024, bhh12 + 1024, u, rg, cr2, hx2);
        lin_phase(wl, hx2, linb, u, rg, m0, t, X, out);

        // ---- argmax over X[0..255][arow] (prob), first-max tie rule ----
        float bv = -1.0f; int bi = 0;
        #pragma unroll
        for (int i = 0; i < 4; i++) {
            int uu = sb * 4 + i;
            float v = X[uu * 16 + arow];
            if (v > bv) { bv = v; bi = uu; }
        }
        redv[sb * 16 + arow] = bv;
        redi[sb * 16 + arow] = bi;
        __syncthreads();
        if (tid < 16) {
            float v0 = redv[tid]; int i0 = redi[tid];
            #pragma unroll 1
            for (int s = 1; s < 64; s++) {
                float v = redv[s * 16 + tid]; int ii = redi[s * 16 + tid];
                if (v > v0 || (v == v0 && ii < i0)) { v0 = v; i0 = ii; }
            }
            outputs[(long long)(m0 + tid) * STEPS + t] = (float)i0;
        }
        // no extra barrier needed: redv/redi next written only after the 8
        // barriers of step t+1's phases; prob/h reads below are read-read.
    }
}

// ---------------------------------------------------------------------------
extern "C" void kernel_launch(void* const* d_in, const int* in_sizes, int n_in,
                              void* d_out, int out_size, void* d_ws, size_t ws_size,
                              hipStream_t stream) {
    const float* tags  = (const float*)d_in[2];
    const float* Wih0  = (const float*)d_in[13];  // [1024, 384]
    const float* Whh0  = (const float*)d_in[14];  // [1024, 256]
    const float* bih0  = (const float*)d_in[15];
    const float* bhh0  = (const float*)d_in[16];
    const float* Wih12 = (const float*)d_in[17];  // [2, 1024, 256]
    const float* Whh12 = (const float*)d_in[18];
    const float* bih12 = (const float*)d_in[19];  // [2, 1024]
    const float* bhh12 = (const float*)d_in[20];
    const float* linW  = (const float*)d_in[21];  // [256, 256]
    const float* linb  = (const float*)d_in[22];

    float* out = (float*)d_out;
    float* ws  = (float*)d_ws;                    // 7.08 MB repacked weights

    repack_kernel<<<WP_TOTAL / 256, 256, 0, stream>>>(Wih0, Whh0, Wih12, Whh12,
                                                      linW, ws);
    decode_kernel<<<Bsz / 16, 1024, 0, stream>>>(
        tags, bih0, bhh0, bih12, bhh12, linb, ws, out);
}

// Round 4
// 7846.586 us; speedup vs baseline: 1.0150x; 1.0150x over previous
//
#include <hip/hip_runtime.h>
#include <math.h>

// ============================================================================
// Seq2Seq decode: fully-fused persistent kernel, v4.
//
// v3 post-mortem: __launch_bounds__(1024) without a min-waves arg let the
// compiler target 8 waves/SIMD -> VGPR capped at 64, but the inner loop
// needs ~80 live (acc16 + w32 + x32) -> the double-buffer got serialized
// (load->wait->use per chunk) and the extra occupancy bought nothing
// (7.96ms vs v2's 7.38ms). Also: gfx950 VALUBusy uses gfx94x SIMD-16
// formulas -> reported 66% is ~33% true issue; kernel is ~90% FMA-pure and
// mostly IDLE waiting on the weight stream. Latency-bound, as theorized.
//
// v4 = v3 + __launch_bounds__(1024, 4): 4 waves/EU -> 1 block/CU -> VGPR
// budget 128 -> intact depth-1 pipeline x 4 independent waves/SIMD
// (~512 cyc issue slack per chunk, covers L2-hit ~300 cyc latency).
// Everything else byte-identical to v3 (verified passing, absmax 0.0039).
//
// Geometry:
//   wave c (0..15) owns gate-cols [c*64, c*64+64); lane: cg = lane&15,
//   rg = lane>>4; thread owns unit u = c*16+cg (4 gates) x 4 rows (rg*4..+3).
//   gate virtual col j (0..3): W row = j*256 + u.
//
// Repacked weights (float4 quads along k): quad = q*1024 + c*64 + j*16 + cg
//   -> per (q,j) a wave reads 16 consecutive quads = 256 B, coalesced.
// lin: quad = q*256 + c*16 + cg (col n = c*16+cg).
//
// LDS X[1152][16]: rows 0..255 prob | 256..383 tags | 384..639 h0 |
//   640..895 h1 | 896..1151 h2. Layer inputs are contiguous row ranges:
//   L0 K=640 rows 0..639; L1 K=512 rows 384..895; L2 K=512 rows 640..1151;
//   lin K=256 rows 896..1151.
// ============================================================================

typedef float v4 __attribute__((ext_vector_type(4)));

constexpr int Bsz   = 4096;
constexpr int AA    = 256;
constexpr int STEPS = 30;
constexpr int LDP   = 31 * AA;                       // 7936
constexpr long long PROB_N = (long long)Bsz * 31 * AA;

constexpr int WP0_Q = 160 * 1024;                    // L0: K=640
constexpr int WP1_Q = 128 * 1024;                    // L1: K=512
constexpr int WP2_Q = 128 * 1024;                    // L2: K=512
constexpr int WPL_Q = 64 * 256;                      // lin: K=256
constexpr int WP1_BASE = WP0_Q;
constexpr int WP2_BASE = WP1_BASE + WP1_Q;
constexpr int WPL_BASE = WP2_BASE + WP2_Q;
constexpr int WP_TOTAL = WPL_BASE + WPL_Q;           // 442368 quads = 7.08 MB

constexpr int XROWS = 1152;

__device__ __forceinline__ float sigf(float x) { return 1.0f / (1.0f + expf(-x)); }

// ---------------------------------------------------------------------------
// One-time weight repack into wave-contiguous layout (v3 mapping).
// ---------------------------------------------------------------------------
__global__ void repack_kernel(const float* __restrict__ Wih0, const float* __restrict__ Whh0,
                              const float* __restrict__ Wih12, const float* __restrict__ Whh12,
                              const float* __restrict__ linW, float* __restrict__ ws)
{
    int t = blockIdx.x * 256 + threadIdx.x;          // quad index, exact grid
    v4 val;
    if (t < WP1_BASE) {                              // layer 0, fused K = 640
        int cg = t & 15, j = (t >> 4) & 3, c = (t >> 6) & 15, q = t >> 10;
        int grow = j * 256 + c * 16 + cg;
        int k4 = q * 4;
        const float* src = (k4 < 384) ? (Wih0 + grow * 384 + k4)          // [prob|tags]
                                      : (Whh0 + grow * 256 + (k4 - 384)); // h0
        val = *reinterpret_cast<const v4*>(src);
    } else if (t < WP2_BASE) {                       // layer 1, K = 512
        int tt = t - WP1_BASE;
        int cg = tt & 15, j = (tt >> 4) & 3, c = (tt >> 6) & 15, q = tt >> 10;
        int grow = j * 256 + c * 16 + cg;
        int k4 = q * 4;
        const float* src = (k4 < 256) ? (Wih12 + grow * 256 + k4)
                                      : (Whh12 + grow * 256 + (k4 - 256));
        val = *reinterpret_cast<const v4*>(src);
    } else if (t < WPL_BASE) {                       // layer 2, K = 512
        int tt = t - WP2_BASE;
        int cg = tt & 15, j = (tt >> 4) & 3, c = (tt >> 6) & 15, q = tt >> 10;
        int grow = j * 256 + c * 16 + cg;
        int k4 = q * 4;
        const float* src = (k4 < 256) ? (Wih12 + 262144 + grow * 256 + k4)
                                      : (Whh12 + 262144 + grow * 256 + (k4 - 256));
        val = *reinterpret_cast<const v4*>(src);
    } else {                                         // lin, K = 256
        int tt = t - WPL_BASE;
        int cg = tt & 15, c = (tt >> 4) & 15, q = tt >> 8;
        int n = c * 16 + cg;
        val = *reinterpret_cast<const v4*>(linW + n * 256 + q * 4);
    }
    reinterpret_cast<v4*>(ws)[t] = val;
}

#define FMA_BLOCK(W, Xv)                                   \
    _Pragma("unroll")                                      \
    for (int k = 0; k < 4; k++)                            \
        _Pragma("unroll")                                  \
        for (int j = 0; j < 4; j++)                        \
            _Pragma("unroll")                              \
            for (int r = 0; r < 4; r++)                    \
                acc[j][r] += W[j][k] * Xv[k][r];

// ---------------------------------------------------------------------------
// LSTM layer phase: GEMM (K = 4*Q) + cell epilogue. Per-thread 1 unit.
// wq: repacked base + c*64 + cg; chunk stride 1024 quads (pointer-bumped).
// ---------------------------------------------------------------------------
template<int Q>
__device__ __forceinline__ void lstm_phase(
    const v4* __restrict__ wq, const float* __restrict__ xb,
    const float* __restrict__ bihL, const float* __restrict__ bhhL,
    int u, int rg, float (&cr)[4], float* __restrict__ dst)
{
    float bs[4];
    #pragma unroll
    for (int j = 0; j < 4; j++) bs[j] = bihL[j * 256 + u] + bhhL[j * 256 + u];

    float acc[4][4];
    #pragma unroll
    for (int j = 0; j < 4; j++)
        #pragma unroll
        for (int r = 0; r < 4; r++) acc[j][r] = 0.0f;

    const v4* xq = reinterpret_cast<const v4*>(xb) + rg;
    const v4* wp = wq;
    v4 wa[4], wb[4], xa[4], xc[4];

    #pragma unroll
    for (int j = 0; j < 4; j++) wa[j] = wp[j * 16];
    wp += 1024;
    #pragma unroll
    for (int k = 0; k < 4; k++) xa[k] = xq[k * 4];

    #pragma unroll 1
    for (int q = 0; q < Q - 2; q += 2) {
        #pragma unroll
        for (int j = 0; j < 4; j++) wb[j] = wp[j * 16];
        wp += 1024;
        #pragma unroll
        for (int k = 0; k < 4; k++) xc[k] = xq[(q + 1) * 16 + k * 4];
        FMA_BLOCK(wa, xa)
        #pragma unroll
        for (int j = 0; j < 4; j++) wa[j] = wp[j * 16];
        wp += 1024;
        #pragma unroll
        for (int k = 0; k < 4; k++) xa[k] = xq[(q + 2) * 16 + k * 4];
        FMA_BLOCK(wb, xc)
    }
    // tail: chunk Q-2 in wa/xa; load and do chunk Q-1
    #pragma unroll
    for (int j = 0; j < 4; j++) wb[j] = wp[j * 16];
    #pragma unroll
    for (int k = 0; k < 4; k++) xc[k] = xq[(Q - 1) * 16 + k * 4];
    FMA_BLOCK(wa, xa)
    FMA_BLOCK(wb, xc)

    __syncthreads();   // all waves done READING xb before h region is overwritten
    v4 hv;
    #pragma unroll
    for (int r = 0; r < 4; r++) {
        float gi = acc[0][r] + bs[0];
        float gf = acc[1][r] + bs[1];
        float gg = acc[2][r] + bs[2];
        float go = acc[3][r] + bs[3];
        float cn = sigf(gf) * cr[r] + sigf(gi) * tanhf(gg);
        cr[r] = cn;
        hv[r] = sigf(go) * tanhf(cn);
    }
    *reinterpret_cast<v4*>(dst + u * 16 + rg * 4) = hv;
    __syncthreads();   // h visible before next phase reads it
}

// ---------------------------------------------------------------------------
// lin phase: pred = sigmoid(h2 @ linW^T + b). Per-thread 1 col (n = u).
// chunk stride 256 quads (pointer-bumped).
// ---------------------------------------------------------------------------
__device__ __forceinline__ void lin_phase(
    const v4* __restrict__ wq, const float* __restrict__ xb,
    const float* __restrict__ linb,
    int n, int rg, int m0, int t,
    float* __restrict__ probdst, float* __restrict__ out)
{
    float b = linb[n];
    float acc[4] = {0.f, 0.f, 0.f, 0.f};
    const v4* xq = reinterpret_cast<const v4*>(xb) + rg;
    const v4* wp = wq;
    v4 wa, wb, xa[4], xc[4];

    wa = wp[0]; wp += 256;
    #pragma unroll
    for (int k = 0; k < 4; k++) xa[k] = xq[k * 4];

    #pragma unroll 1
    for (int q = 0; q < 62; q += 2) {
        wb = wp[0]; wp += 256;
        #pragma unroll
        for (int k = 0; k < 4; k++) xc[k] = xq[(q + 1) * 16 + k * 4];
        #pragma unroll
        for (int k = 0; k < 4; k++)
            #pragma unroll
            for (int r = 0; r < 4; r++) acc[r] += wa[k] * xa[k][r];
        wa = wp[0]; wp += 256;
        #pragma unroll
        for (int k = 0; k < 4; k++) xa[k] = xq[(q + 2) * 16 + k * 4];
        #pragma unroll
        for (int k = 0; k < 4; k++)
            #pragma unroll
            for (int r = 0; r < 4; r++) acc[r] += wb[k] * xc[k][r];
    }
    wb = wp[0];
    #pragma unroll
    for (int k = 0; k < 4; k++) xc[k] = xq[63 * 16 + k * 4];
    #pragma unroll
    for (int k = 0; k < 4; k++)
        #pragma unroll
        for (int r = 0; r < 4; r++) acc[r] += wa[k] * xa[k][r];
    #pragma unroll
    for (int k = 0; k < 4; k++)
        #pragma unroll
        for (int r = 0; r < 4; r++) acc[r] += wb[k] * xc[k][r];

    __syncthreads();   // everyone done reading h2; old prob no longer needed
    v4 pv;
    #pragma unroll
    for (int r = 0; r < 4; r++) pv[r] = sigf(acc[r] + b);
    *reinterpret_cast<v4*>(probdst + n * 16 + rg * 4) = pv;
    #pragma unroll
    for (int r = 0; r < 4; r++)
        out[(long long)(m0 + rg * 4 + r) * LDP + (long long)(t + 1) * AA + n] = pv[r];
    __syncthreads();   // prob LDS visible for argmax + next step
}

// ---------------------------------------------------------------------------
// Persistent decode kernel: 256 blocks x 16 rows, 16 waves, 30 steps fused.
// __launch_bounds__(1024, 4): 4 waves/EU -> VGPR budget 128 (v3's missing
// second arg let the compiler cap at 64 and serialize the pipeline).
// ---------------------------------------------------------------------------
__global__ __launch_bounds__(1024, 4) void decode_kernel(
    const float* __restrict__ tags,
    const float* __restrict__ bih0, const float* __restrict__ bhh0,
    const float* __restrict__ bih12, const float* __restrict__ bhh12,
    const float* __restrict__ linb,
    const float* __restrict__ ws,
    float* __restrict__ out)
{
    __shared__ float X[XROWS * 16];      // 73728 B
    __shared__ float redv[1024];         // argmax partials [64 sb][16 rows]
    __shared__ int   redi[1024];

    const int tid  = threadIdx.x;
    const int c    = tid >> 6;
    const int lane = tid & 63;
    const int cg   = lane & 15;
    const int rg   = lane >> 4;
    const int u    = c * 16 + cg;
    const int m0   = blockIdx.x * 16;

    // ---- init: zero state, stage tags, one-hot(START=1) ----
    for (int i = tid; i < XROWS * 16; i += 1024) X[i] = 0.0f;
    __syncthreads();
    for (int i = tid; i < 128 * 16; i += 1024) {
        int m = i & 15, k = i >> 4;
        X[(256 + k) * 16 + m] = tags[(long long)(m0 + m) * 128 + k];
    }
    if (tid < 16) X[1 * 16 + tid] = 1.0f;                    // prob one-hot col 1
    for (int i = tid; i < 256 * 16; i += 1024) {
        int m = i >> 8, col = i & 255;
        out[(long long)(m0 + m) * LDP + col] = (col == 1) ? 1.0f : 0.0f;
    }
    __syncthreads();

    float cr0[4], cr1[4], cr2[4];
    #pragma unroll
    for (int r = 0; r < 4; r++) { cr0[r] = 0.f; cr1[r] = 0.f; cr2[r] = 0.f; }

    const v4* wsq = reinterpret_cast<const v4*>(ws);
    const v4* w0 = wsq + 0        + c * 64 + cg;
    const v4* w1 = wsq + WP1_BASE + c * 64 + cg;
    const v4* w2 = wsq + WP2_BASE + c * 64 + cg;
    const v4* wl = wsq + WPL_BASE + c * 16 + cg;

    float* hx0 = X + 384 * 16;   // h0 rows
    float* hx1 = X + 640 * 16;   // h1 rows
    float* hx2 = X + 896 * 16;   // h2 rows

    const int arow = tid & 15, sb = tid >> 4;    // sb in 0..63
    float* outputs = out + PROB_N;

    #pragma unroll 1
    for (int t = 0; t < STEPS; t++) {
        lstm_phase<160>(w0, X,   bih0,         bhh0,         u, rg, cr0, hx0);
        lstm_phase<128>(w1, hx0, bih12,        bhh12,        u, rg, cr1, hx1);
        lstm_phase<128>(w2, hx1, bih12 + 1024, bhh12 + 1024, u, rg, cr2, hx2);
        lin_phase(wl, hx2, linb, u, rg, m0, t, X, out);

        // ---- argmax over X[0..255][arow] (prob), first-max tie rule ----
        float bv = -1.0f; int bi = 0;
        #pragma unroll
        for (int i = 0; i < 4; i++) {
            int uu = sb * 4 + i;
            float v = X[uu * 16 + arow];
            if (v > bv) { bv = v; bi = uu; }
        }
        redv[sb * 16 + arow] = bv;
        redi[sb * 16 + arow] = bi;
        __syncthreads();
        if (tid < 16) {
            float v0 = redv[tid]; int i0 = redi[tid];
            #pragma unroll 1
            for (int s = 1; s < 64; s++) {
                float v = redv[s * 16 + tid]; int ii = redi[s * 16 + tid];
                if (v > v0 || (v == v0 && ii < i0)) { v0 = v; i0 = ii; }
            }
            outputs[(long long)(m0 + tid) * STEPS + t] = (float)i0;
        }
        // no extra barrier needed: redv/redi next written only after the 8
        // barriers of step t+1's phases; prob/h reads below are read-read.
    }
}

// ---------------------------------------------------------------------------
extern "C" void kernel_launch(void* const* d_in, const int* in_sizes, int n_in,
                              void* d_out, int out_size, void* d_ws, size_t ws_size,
                              hipStream_t stream) {
    const float* tags  = (const float*)d_in[2];
    const float* Wih0  = (const float*)d_in[13];  // [1024, 384]
    const float* Whh0  = (const float*)d_in[14];  // [1024, 256]
    const float* bih0  = (const float*)d_in[15];
    const float* bhh0  = (const float*)d_in[16];
    const float* Wih12 = (const float*)d_in[17];  // [2, 1024, 256]
    const float* Whh12 = (const float*)d_in[18];
    const float* bih12 = (const float*)d_in[19];  // [2, 1024]
    const float* bhh12 = (const float*)d_in[20];
    const float* linW  = (const float*)d_in[21];  // [256, 256]
    const float* linb  = (const float*)d_in[22];

    float* out = (float*)d_out;
    float* ws  = (float*)d_ws;                    // 7.08 MB repacked weights

    repack_kernel<<<WP_TOTAL / 256, 256, 0, stream>>>(Wih0, Whh0, Wih12, Whh12,
                                                      linW, ws);
    decode_kernel<<<Bsz / 16, 1024, 0, stream>>>(
        tags, bih0, bhh0, bih12, bhh12, linb, ws, out);
}

// Round 5
// 7341.822 us; speedup vs baseline: 1.0847x; 1.0688x over previous
//
#include <hip/hip_runtime.h>
#include <math.h>

// ============================================================================
// Seq2Seq decode: fully-fused persistent kernel, v5 — async weight DMA.
//
// v3/v4 post-mortem: the compiler refuses to hold a VGPR-resident weight
// double-buffer (VGPR_Count stayed 64 even with launch_bounds(1024,4) giving
// a 128 budget; regalloc minimizes to its occupancy target). The weight
// stream is latency-bound (sweep 7MB/step > 4MB XCD L2 -> every chunk is an
// L2 miss ~500-900cyc) and the serialized load->wait->FMA loop exposes it.
//
// v5: weights arrive via __builtin_amdgcn_global_load_lds (VGPR-free DMA)
// into a 4-buffer LDS ring with hand-counted s_waitcnt vmcnt(N) (prefetch
// depth 3; never drain to 0 mid-loop). KEY: the repacked layout makes wave c
// consume exactly the 64 quads/chunk it stages -> each wave runs a PRIVATE
// ring slice (1KB/buf), no cross-wave deps, no extra barriers. lin is folded
// into the same ring by staging 4 chunks per DMA (lane rg = sub-chunk).
// FMA order per output unchanged -> absmax must stay 0.00390625.
//
// Geometry (unchanged from v3/v4):
//   1024 thr = 16 waves; wave c owns gate-cols [c*64, c*64+64); cg=lane&15,
//   rg=lane>>4; thread = unit u=c*16+cg (4 gates) x 4 rows (rg*4..+3).
//   Repacked weights: quad = q*1024 + c*64 + j*16 + cg (LSTM),
//                     quad = q*256  + c*16 + cg        (lin).
//   LDS X[1152][16]: prob | tags | h0 | h1 | h2 (contiguous K-ranges).
// ============================================================================

typedef float v4 __attribute__((ext_vector_type(4)));

constexpr int Bsz   = 4096;
constexpr int AA    = 256;
constexpr int STEPS = 30;
constexpr int LDP   = 31 * AA;                       // 7936
constexpr long long PROB_N = (long long)Bsz * 31 * AA;

constexpr int WP0_Q = 160 * 1024;                    // L0: K=640
constexpr int WP1_Q = 128 * 1024;                    // L1: K=512
constexpr int WP2_Q = 128 * 1024;                    // L2: K=512
constexpr int WPL_Q = 64 * 256;                      // lin: K=256
constexpr int WP1_BASE = WP0_Q;
constexpr int WP2_BASE = WP1_BASE + WP1_Q;
constexpr int WPL_BASE = WP2_BASE + WP2_Q;
constexpr int WP_TOTAL = WPL_BASE + WPL_Q;           // 442368 quads = 7.08 MB

constexpr int XROWS = 1152;

__device__ __forceinline__ float sigf(float x) { return 1.0f / (1.0f + expf(-x)); }

// async 16B/lane global->LDS DMA (lds dest = wave-uniform base + lane*16)
__device__ __forceinline__ void gld16(const float* g, float* l) {
    __builtin_amdgcn_global_load_lds(
        (const __attribute__((address_space(1))) float*)g,
        (__attribute__((address_space(3))) float*)l,
        16, 0, 0);
}

#define WAITVM(n) asm volatile("s_waitcnt vmcnt(" #n ")" ::: "memory")

// ---------------------------------------------------------------------------
// One-time weight repack into wave-contiguous layout (v3 mapping, unchanged).
// ---------------------------------------------------------------------------
__global__ void repack_kernel(const float* __restrict__ Wih0, const float* __restrict__ Whh0,
                              const float* __restrict__ Wih12, const float* __restrict__ Whh12,
                              const float* __restrict__ linW, float* __restrict__ ws)
{
    int t = blockIdx.x * 256 + threadIdx.x;          // quad index, exact grid
    v4 val;
    if (t < WP1_BASE) {                              // layer 0, fused K = 640
        int cg = t & 15, j = (t >> 4) & 3, c = (t >> 6) & 15, q = t >> 10;
        int grow = j * 256 + c * 16 + cg;
        int k4 = q * 4;
        const float* src = (k4 < 384) ? (Wih0 + grow * 384 + k4)          // [prob|tags]
                                      : (Whh0 + grow * 256 + (k4 - 384)); // h0
        val = *reinterpret_cast<const v4*>(src);
    } else if (t < WP2_BASE) {                       // layer 1, K = 512
        int tt = t - WP1_BASE;
        int cg = tt & 15, j = (tt >> 4) & 3, c = (tt >> 6) & 15, q = tt >> 10;
        int grow = j * 256 + c * 16 + cg;
        int k4 = q * 4;
        const float* src = (k4 < 256) ? (Wih12 + grow * 256 + k4)
                                      : (Whh12 + grow * 256 + (k4 - 256));
        val = *reinterpret_cast<const v4*>(src);
    } else if (t < WPL_BASE) {                       // layer 2, K = 512
        int tt = t - WP2_BASE;
        int cg = tt & 15, j = (tt >> 4) & 3, c = (tt >> 6) & 15, q = tt >> 10;
        int grow = j * 256 + c * 16 + cg;
        int k4 = q * 4;
        const float* src = (k4 < 256) ? (Wih12 + 262144 + grow * 256 + k4)
                                      : (Whh12 + 262144 + grow * 256 + (k4 - 256));
        val = *reinterpret_cast<const v4*>(src);
    } else {                                         // lin, K = 256
        int tt = t - WPL_BASE;
        int cg = tt & 15, c = (tt >> 4) & 15, q = tt >> 8;
        int n = c * 16 + cg;
        val = *reinterpret_cast<const v4*>(linW + n * 256 + q * 4);
    }
    reinterpret_cast<v4*>(ws)[t] = val;
}

// consume one LSTM chunk q from ring buf (q&3): 4 w-quads + 4 x-quads + 64 FMA
#define LSTM_CHUNK(q)                                                          \
    {                                                                          \
        const v4* wv_ = (const v4*)(wbuf + (((q) & 3) << 12)) + cg;            \
        v4 w_[4], x_[4];                                                       \
        _Pragma("unroll") for (int j = 0; j < 4; j++) w_[j] = wv_[j * 16];     \
        _Pragma("unroll") for (int k = 0; k < 4; k++) x_[k] = xq[(q) * 16 + k * 4]; \
        _Pragma("unroll") for (int k = 0; k < 4; k++)                          \
            _Pragma("unroll") for (int j = 0; j < 4; j++)                      \
                _Pragma("unroll") for (int r = 0; r < 4; r++)                  \
                    acc[j][r] += w_[j][k] * x_[k][r];                          \
    }

// consume one lin group g (4 sub-chunks) from ring buf (g&3)
#define LIN_GROUP(g)                                                           \
    {                                                                          \
        const v4* wv_ = (const v4*)(wbuf + (((g) & 3) << 12)) + cg;            \
        _Pragma("unroll") for (int s = 0; s < 4; s++) {                        \
            v4 w_ = wv_[s * 16];                                               \
            v4 x_[4];                                                          \
            _Pragma("unroll") for (int k = 0; k < 4; k++)                      \
                x_[k] = xq[((g) * 4 + s) * 16 + k * 4];                        \
            _Pragma("unroll") for (int k = 0; k < 4; k++)                      \
                _Pragma("unroll") for (int r = 0; r < 4; r++)                  \
                    acc[r] += w_[k] * x_[k][r];                                \
        }                                                                      \
    }

// ---------------------------------------------------------------------------
// LSTM layer phase, async: GEMM (K = 4*Q) + cell epilogue.
// wg  : per-thread global src = layer base + (c*64+lane)*4 floats
// wbuf: per-wave LDS ring base = wring + c*256 (bufs at +b*4096 floats)
// ---------------------------------------------------------------------------
template<int Q>
__device__ __forceinline__ void lstm_phase_async(
    const float* __restrict__ wg, float* __restrict__ wbuf,
    const float* __restrict__ xb,
    const float* __restrict__ bihL, const float* __restrict__ bhhL,
    int u, int rg, int cg, float (&cr)[4], float* __restrict__ dst)
{
    float bs[4];
    #pragma unroll
    for (int j = 0; j < 4; j++) bs[j] = bihL[j * 256 + u] + bhhL[j * 256 + u];

    float acc[4][4];
    #pragma unroll
    for (int j = 0; j < 4; j++)
        #pragma unroll
        for (int r = 0; r < 4; r++) acc[j][r] = 0.0f;

    const v4* xq = reinterpret_cast<const v4*>(xb) + rg;

    // prologue: 3 chunks in flight
    gld16(wg,            wbuf);
    gld16(wg +  1 * 4096, wbuf + 1 * 4096);
    gld16(wg +  2 * 4096, wbuf + 2 * 4096);

    #pragma unroll 1
    for (int q = 0; q < Q - 3; q++) {
        gld16(wg + (q + 3) * 4096, wbuf + (((q + 3) & 3) << 12));
        WAITVM(3);                       // chunk q's DMA complete
        LSTM_CHUNK(q)
    }
    WAITVM(2); LSTM_CHUNK(Q - 3)
    WAITVM(1); LSTM_CHUNK(Q - 2)
    WAITVM(0); LSTM_CHUNK(Q - 1)

    __syncthreads();   // all waves done READING xb before h region is overwritten
    v4 hv;
    #pragma unroll
    for (int r = 0; r < 4; r++) {
        float gi = acc[0][r] + bs[0];
        float gf = acc[1][r] + bs[1];
        float gg = acc[2][r] + bs[2];
        float go = acc[3][r] + bs[3];
        float cn = sigf(gf) * cr[r] + sigf(gi) * tanhf(gg);
        cr[r] = cn;
        hv[r] = sigf(go) * tanhf(cn);
    }
    *reinterpret_cast<v4*>(dst + u * 16 + rg * 4) = hv;
    __syncthreads();   // h visible before next phase reads it
}

// ---------------------------------------------------------------------------
// lin phase, async: pred = sigmoid(h2 @ linW^T + b). 16 groups of 4 chunks;
// one DMA per group (lane rg stages sub-chunk rg of the wave's col slice).
// wg: per-thread global src = WPL base + (rg*256 + c*16 + cg)*4 floats.
// ---------------------------------------------------------------------------
__device__ __forceinline__ void lin_phase_async(
    const float* __restrict__ wg, float* __restrict__ wbuf,
    const float* __restrict__ xb, const float* __restrict__ linb,
    int n, int rg, int cg, int m0, int t,
    float* __restrict__ probdst, float* __restrict__ out)
{
    float b = linb[n];
    float acc[4] = {0.f, 0.f, 0.f, 0.f};
    const v4* xq = reinterpret_cast<const v4*>(xb) + rg;

    gld16(wg,            wbuf);
    gld16(wg + 1 * 4096, wbuf + 1 * 4096);
    gld16(wg + 2 * 4096, wbuf + 2 * 4096);

    #pragma unroll 1
    for (int g = 0; g < 13; g++) {
        gld16(wg + (g + 3) * 4096, wbuf + (((g + 3) & 3) << 12));
        WAITVM(3);
        LIN_GROUP(g)
    }
    WAITVM(2); LIN_GROUP(13)
    WAITVM(1); LIN_GROUP(14)
    WAITVM(0); LIN_GROUP(15)

    __syncthreads();   // everyone done reading h2; old prob no longer needed
    v4 pv;
    #pragma unroll
    for (int r = 0; r < 4; r++) pv[r] = sigf(acc[r] + b);
    *reinterpret_cast<v4*>(probdst + n * 16 + rg * 4) = pv;
    #pragma unroll
    for (int r = 0; r < 4; r++)
        out[(long long)(m0 + rg * 4 + r) * LDP + (long long)(t + 1) * AA + n] = pv[r];
    __syncthreads();   // prob LDS visible for argmax + next step
}

// ---------------------------------------------------------------------------
// Persistent decode kernel: 256 blocks x 16 rows, 16 waves, 30 steps fused.
// ---------------------------------------------------------------------------
__global__ __launch_bounds__(1024, 4) void decode_kernel(
    const float* __restrict__ tags,
    const float* __restrict__ bih0, const float* __restrict__ bhh0,
    const float* __restrict__ bih12, const float* __restrict__ bhh12,
    const float* __restrict__ linb,
    const float* __restrict__ ws,
    float* __restrict__ out)
{
    __shared__ float X[XROWS * 16];      // 73728 B
    __shared__ float wring[4 * 4096];    // 65536 B: 4-buf DMA ring (1KB/wave/buf)
    __shared__ float redv[1024];         // argmax partials [64 sb][16 rows]
    __shared__ int   redi[1024];

    const int tid  = threadIdx.x;
    const int c    = tid >> 6;
    const int lane = tid & 63;
    const int cg   = lane & 15;
    const int rg   = lane >> 4;
    const int u    = c * 16 + cg;
    const int m0   = blockIdx.x * 16;

    // ---- init: zero state, stage tags, one-hot(START=1) ----
    for (int i = tid; i < XROWS * 16; i += 1024) X[i] = 0.0f;
    __syncthreads();
    for (int i = tid; i < 128 * 16; i += 1024) {
        int m = i & 15, k = i >> 4;
        X[(256 + k) * 16 + m] = tags[(long long)(m0 + m) * 128 + k];
    }
    if (tid < 16) X[1 * 16 + tid] = 1.0f;                    // prob one-hot col 1
    for (int i = tid; i < 256 * 16; i += 1024) {
        int m = i >> 8, col = i & 255;
        out[(long long)(m0 + m) * LDP + col] = (col == 1) ? 1.0f : 0.0f;
    }
    __syncthreads();

    float cr0[4], cr1[4], cr2[4];
    #pragma unroll
    for (int r = 0; r < 4; r++) { cr0[r] = 0.f; cr1[r] = 0.f; cr2[r] = 0.f; }

    // per-thread global DMA sources (float offsets)
    const float* w0g = ws + ((c * 64 + lane) << 2);
    const float* w1g = ws + 4 * WP1_BASE + ((c * 64 + lane) << 2);
    const float* w2g = ws + 4 * WP2_BASE + ((c * 64 + lane) << 2);
    const float* wlg = ws + 4 * WPL_BASE + ((rg * 256 + c * 16 + cg) << 2);
    // per-wave LDS ring slice
    float* wbuf = wring + c * 256;

    float* hx0 = X + 384 * 16;   // h0 rows
    float* hx1 = X + 640 * 16;   // h1 rows
    float* hx2 = X + 896 * 16;   // h2 rows

    const int arow = tid & 15, sb = tid >> 4;    // sb in 0..63
    float* outputs = out + PROB_N;

    #pragma unroll 1
    for (int t = 0; t < STEPS; t++) {
        lstm_phase_async<160>(w0g, wbuf, X,   bih0,         bhh0,         u, rg, cg, cr0, hx0);
        lstm_phase_async<128>(w1g, wbuf, hx0, bih12,        bhh12,        u, rg, cg, cr1, hx1);
        lstm_phase_async<128>(w2g, wbuf, hx1, bih12 + 1024, bhh12 + 1024, u, rg, cg, cr2, hx2);
        lin_phase_async(wlg, wbuf, hx2, linb, u, rg, cg, m0, t, X, out);

        // ---- argmax over X[0..255][arow] (prob), first-max tie rule ----
        float bv = -1.0f; int bi = 0;
        #pragma unroll
        for (int i = 0; i < 4; i++) {
            int uu = sb * 4 + i;
            float v = X[uu * 16 + arow];
            if (v > bv) { bv = v; bi = uu; }
        }
        redv[sb * 16 + arow] = bv;
        redi[sb * 16 + arow] = bi;
        __syncthreads();
        if (tid < 16) {
            float v0 = redv[tid]; int i0 = redi[tid];
            #pragma unroll 1
            for (int s = 1; s < 64; s++) {
                float v = redv[s * 16 + tid]; int ii = redi[s * 16 + tid];
                if (v > v0 || (v == v0 && ii < i0)) { v0 = v; i0 = ii; }
            }
            outputs[(long long)(m0 + tid) * STEPS + t] = (float)i0;
        }
        // no extra barrier needed: redv/redi next written only after the 8
        // barriers of step t+1's phases; prob/h reads below are read-read.
    }
}

// ---------------------------------------------------------------------------
extern "C" void kernel_launch(void* const* d_in, const int* in_sizes, int n_in,
                              void* d_out, int out_size, void* d_ws, size_t ws_size,
                              hipStream_t stream) {
    const float* tags  = (const float*)d_in[2];
    const float* Wih0  = (const float*)d_in[13];  // [1024, 384]
    const float* Whh0  = (const float*)d_in[14];  // [1024, 256]
    const float* bih0  = (const float*)d_in[15];
    const float* bhh0  = (const float*)d_in[16];
    const float* Wih12 = (const float*)d_in[17];  // [2, 1024, 256]
    const float* Whh12 = (const float*)d_in[18];
    const float* bih12 = (const float*)d_in[19];  // [2, 1024]
    const float* bhh12 = (const float*)d_in[20];
    const float* linW  = (const float*)d_in[21];  // [256, 256]
    const float* linb  = (const float*)d_in[22];

    float* out = (float*)d_out;
    float* ws  = (float*)d_ws;                    // 7.08 MB repacked weights

    repack_kernel<<<WP_TOTAL / 256, 256, 0, stream>>>(Wih0, Whh0, Wih12, Whh12,
                                                      linW, ws);
    decode_kernel<<<Bsz / 16, 1024, 0, stream>>>(
        tags, bih0, bhh0, bih12, bhh12, linb, ws, out);
}